// Round 13
// baseline (125.817 us; speedup 1.0000x reference)
//
#include <hip/hip_runtime.h>
#include <stdint.h>

#define BATCH 32
#define H 512
#define W 512
#define NACC 16
#define TH 32              // center rows per tile
#define HALO 9             // coverage steps a=1..9
#define RH (TH + 2*HALO)   // 50 rows incl. halo
#define NWORDS (RH*8)      // 400 mask words per image
#define NT 1024
#define NW (NT/64)         // 16 waves
#define NTILE (H/TH)       // 16
#define NBLK (NTILE*BATCH) // 512 blocks = 2/CU

// part[fid*NACC + k] per-block partials (no atomics, deterministic):
//  0: sum(p*g)  1: sum(p)  2: sum(g)
//  3: cnt_pe 4: cnt_pm 5: cnt_pj  6: cnt_ge 7: cnt_gm 8: cnt_gj
//  9: int_e 10: int_m 11: int_j
// 12: dsum_p2g 13: cnt_p2g 14: dsum_g2p 15: cnt_g2p

// LB(NT,8) forces a 64-VGPR budget -> backend spills ~118MB (R7/R8).
// LB(NT,4) -> R9 compiled 32 VGPR, zero spill. Spend headroom on MLP.
__global__ __launch_bounds__(NT, 4) void fused_kernel(
    const float* __restrict__ pred, const float* __restrict__ gt,
    float* __restrict__ part)
{
    __shared__ uint64_t Mp[2][RH][8];    // pred mask, double-buffered
    __shared__ uint64_t Mg[2][RH][8];    // gt mask
    __shared__ float    EC[2][TH];       // pred colsums at cols 255|256
    __shared__ float    red[NW][16];

    // fid = tile*32 + b: vertically-adjacent tiles of one image are 32 apart
    // => same XCD under mod-8 round-robin dispatch (halo rows share L2).
    int fid  = blockIdx.x;
    int b    = fid & 31;
    int tile = fid >> 5;

    const float* pimg = pred + (size_t)b * H * W;
    const float* gimg = gt   + (size_t)b * H * W;
    int y0 = tile * TH;
    int tid = threadIdx.x, lane = tid & 63, wid = tid >> 6;

    uint64_t* Mp0 = &Mp[0][0][0];
    uint64_t* Mg0 = &Mg[0][0][0];

    // ---- Phase 1: ballot masks + dice sums, rows y0-9..y0+40.
    // 400 word-tasks, x4 unroll: 8 global loads in flight per wave iteration.
    float v0 = 0.f, v1 = 0.f;
    for (int s0 = wid; s0 < NWORDS; s0 += 4 * NW) {
        float vp[4], vg[4];
        #pragma unroll
        for (int u = 0; u < 4; ++u) {
            int s = s0 + u * NW;
            vp[u] = 0.f; vg[u] = 0.f;
            int ry = y0 - HALO + (s >> 3);
            if (s < NWORDS && (unsigned)ry < (unsigned)H) {
                int i0 = ry * W + (s & 7) * 64 + lane;
                vp[u] = pimg[i0]; vg[u] = gimg[i0];
            }
        }
        #pragma unroll
        for (int u = 0; u < 4; ++u) {
            int s = s0 + u * NW;
            if (s < NWORDS) {                 // wave-uniform
                unsigned long long mp = __ballot(vp[u] > 0.5f);
                unsigned long long mg = __ballot(vg[u] > 0.5f);
                if (lane == 0) { Mp0[s] = mp; Mg0[s] = mg; }
                int r = s >> 3;
                if (r >= HALO && r < HALO + TH) {
                    v1 += vp[u];
                    v0 += (vg[u] > 0.5f) ? vp[u] : 0.f;
                }
            }
        }
    }

    // ---- Pre-barrier prefetch: first two stencil rows (latency overlaps
    // the barrier drain instead of serializing after it)
    int qi = tid & 127, h = tid >> 7;     // h in 0..7, 4 rows each
    int x4 = qi * 4;
    int ys = y0 + h * 4;
    float4 pm4 = (ys > 0) ? *(const float4*)(pimg + (size_t)(ys - 1) * W + x4)
                          : make_float4(0, 0, 0, 0);
    float4 pc4 = *(const float4*)(pimg + (size_t)ys * W + x4);

    // pred edge colsums (cols 255,256) for the cross-wave stencil halo
    if (tid < 2 * TH) {
        int c = tid >> 5, r = tid & (TH - 1);
        int y = y0 + r, col = 255 + c;
        float sum = (y > 0     ? pimg[(size_t)(y - 1) * W + col] : 0.f)
                  +              pimg[(size_t)y * W + col]
                  + (y < H - 1 ? pimg[(size_t)(y + 1) * W + col] : 0.f);
        EC[c][r] = sum;
    }
    __syncthreads();

    // ---- Target bits for distance (center 32 rows = 256 words, tid<256)
    uint64_t Tp = 0ULL, Tg = 0ULL;
    int rT = HALO + (tid >> 3), wT = tid & 7;
    if (tid < TH * 8) { Tp = Mp[0][rT][wT]; Tg = Mg[0][rT][wT]; }
    int dcnt_p = __popcll(Tp), dcnt_g = __popcll(Tg);
    int dsum_p = dcnt_p, dsum_g = dcnt_g;   // a=0 baseline (dist >= 1)

    // ---- Stencil: pred via floats (rolling rows), gt via bit popcounts.
    // 9 classification counters packed into one u64 (7-bit fields, max 16/thr)
    uint64_t cpack = 0ULL;
    {
        int wdx = qi >> 4;                    // gt word for this quad
        int ss = (qi & 15) * 4;               // bit offset of x4 in word

        auto win6 = [&](int rb) -> uint32_t {
            const uint64_t* row = Mg[0][rb];
            uint64_t bm = row[wdx];
            if (ss == 0) {
                uint64_t lo = wdx ? row[wdx - 1] : 0ULL;
                return (uint32_t)(((bm << 1) | (lo >> 63)) & 0x3FULL);
            }
            uint32_t v = (uint32_t)((bm >> (ss - 1)) & 0x3FULL);
            if (ss == 60) {
                uint64_t hi = (wdx < 7) ? row[wdx + 1] : 0ULL;
                v |= ((uint32_t)hi & 1u) << 5;
            }
            return v;
        };

        int rb0 = h * 4 + HALO - 1;           // bit-row of (ys-1)
        uint32_t wU = win6(rb0), wM = win6(rb0 + 1);

        for (int r = 0; r < 4; ++r) {
            int y = ys + r;
            float4 pp4 = (y < H - 1) ? *(const float4*)(pimg + (size_t)(y + 1) * W + x4)
                                     : make_float4(0, 0, 0, 0);
            uint32_t wD = win6(rb0 + 2 + r);
            int ry = h * 4 + r;

            float ps[6];
            ps[1] = pm4.x + pc4.x + pp4.x; ps[2] = pm4.y + pc4.y + pp4.y;
            ps[3] = pm4.z + pc4.z + pp4.z; ps[4] = pm4.w + pc4.w + pp4.w;
            float psl = __shfl_up(ps[4], 1, 64);
            float psr = __shfl_down(ps[1], 1, 64);
            if (lane == 0)  psl = (qi == 0)   ? 0.f : EC[0][ry];
            if (lane == 63) psr = (qi == 127) ? 0.f : EC[1][ry];
            ps[0] = psl; ps[5] = psr;

            float pcv[4] = {pc4.x, pc4.y, pc4.z, pc4.w};
            #pragma unroll
            for (int j = 0; j < 4; ++j) {
                float np = ps[j] + ps[j + 1] + ps[j + 2] - pcv[j];
                bool pon = pcv[j] > 0.5f;
                bool pe  = pon && (np == 1.f);
                bool pmb = pon && (np == 2.f);
                bool pjb = pon && (np > 2.f);
                uint32_t n9 = ((wU >> j) & 7u) | (((wM >> j) & 7u) << 3) | (((wD >> j) & 7u) << 6);
                uint32_t cen = (wM >> (j + 1)) & 1u;
                int ng = __popc(n9) - (int)cen;
                bool gon = cen != 0u;
                bool ge  = gon && (ng == 1);
                bool gmb = gon && (ng == 2);
                bool gjb = gon && (ng > 2);
                cpack += (uint64_t)pe
                       | ((uint64_t)pmb << 7)
                       | ((uint64_t)pjb << 14)
                       | ((uint64_t)ge  << 21)
                       | ((uint64_t)gmb << 28)
                       | ((uint64_t)gjb << 35)
                       | ((uint64_t)(pe  && ge)  << 42)
                       | ((uint64_t)(pmb && gmb) << 49)
                       | ((uint64_t)(pjb && gjb) << 56);
            }
            pm4 = pc4; pc4 = pp4; wU = wM; wM = wD;
        }
    }

    // ---- 9 bit-dilation steps: p/g split across thread halves, shrinking
    // active rows (step a only needs rows [a, RH-1-a]); popcount after each.
    int cur = 0;
    int half = tid >> 9;           // 0: pred mask, 1: gt mask
    int t    = tid & 511;
    for (int a = 1; a <= 9; ++a) {
        int ntask = (RH - 2 * a) * 8;        // 384..256, multiple of 16
        if (t < ntask) {
            int r = a + (t >> 3), w = t & 7;
            uint64_t (*Msrc)[8] = half ? Mg[cur] : Mp[cur];
            uint64_t (*Mdst)[8] = half ? Mg[cur ^ 1] : Mp[cur ^ 1];
            uint64_t X = Msrc[r - 1][w] | Msrc[r][w] | Msrc[r + 1][w];
            uint32_t lm = __shfl_up  ((uint32_t)(X >> 63), 1, 64);
            uint32_t rl = __shfl_down((uint32_t)(X & 1ULL), 1, 64);
            uint64_t Y = X | (X << 1) | (X >> 1);
            if (w > 0) Y |= (uint64_t)(lm & 1u);
            if (w < 7) Y |= ((uint64_t)(rl & 1u)) << 63;
            Mdst[r][w] = Y;
        }
        __syncthreads();
        cur ^= 1;
        if (tid < TH * 8) {
            dsum_p += __popcll(Tp & ~Mg[cur][rT][wT]);  // pred targets vs gt coverage
            dsum_g += __popcll(Tg & ~Mp[cur][rT][wT]);  // gt targets vs pred coverage
        }
    }

    // ---- Reductions -> per-block partials (no atomics)
    float vals[16];
    vals[0] = v0; vals[1] = v1;
    vals[2]  = (float)dcnt_g;                 // sum(g) = popc of gt targets
    vals[3]  = (float)((cpack      ) & 0x7F);
    vals[4]  = (float)((cpack >> 7 ) & 0x7F);
    vals[5]  = (float)((cpack >> 14) & 0x7F);
    vals[6]  = (float)((cpack >> 21) & 0x7F);
    vals[7]  = (float)((cpack >> 28) & 0x7F);
    vals[8]  = (float)((cpack >> 35) & 0x7F);
    vals[9]  = (float)((cpack >> 42) & 0x7F);
    vals[10] = (float)((cpack >> 49) & 0x7F);
    vals[11] = (float)((cpack >> 56) & 0x7F);
    vals[12] = (float)dsum_p; vals[13] = (float)dcnt_p;
    vals[14] = (float)dsum_g; vals[15] = (float)dcnt_g;
    #pragma unroll
    for (int j = 0; j < 16; ++j)
        #pragma unroll
        for (int off = 32; off; off >>= 1)
            vals[j] += __shfl_down(vals[j], off, 64);
    if (lane == 0) {
        #pragma unroll
        for (int j = 0; j < 16; ++j) red[wid][j] = vals[j];
    }
    __syncthreads();
    if (tid < 16) {
        float s = 0.f;
        #pragma unroll
        for (int wv = 0; wv < NW; ++wv) s += red[wv][tid];
        part[fid * NACC + tid] = s;
    }
}

// ---------------------------------------------------------------------------
// Final: reduce 512x16 partials -> 32x16 -> scalar. One block, deterministic.
// ---------------------------------------------------------------------------
__global__ __launch_bounds__(512) void final_kernel(
    const float* __restrict__ part, float* __restrict__ out)
{
    __shared__ float sacc[BATCH][NACC];
    __shared__ float tri[BATCH][3];
    int t = threadIdx.x;
    {
        int b = t >> 4, k = t & 15;
        float s = 0.f;
        #pragma unroll 4
        for (int j = 0; j < NTILE; ++j)            // fid = j*32 + b
            s += part[((j << 5) + b) * NACC + k];
        sacc[b][k] = s;
    }
    __syncthreads();
    if (t < BATCH) {
        const float* a = sacc[t];
        float inter = a[0], psum = a[1], gsum = a[2];
        float dice = (2.f * inter + 1.f) / (psum + gsum + 1.f);

        float pe = a[3], pm = a[4], pj = a[5];
        float ge = a[6], gm = a[7], gj = a[8];
        float ie = a[9], im = a[10], ij = a[11];
        float e_iou = (ie + 1.f) / (pe + ge - ie + 1.f);
        float m_iou = (im + 1.f) / (pm + gm - im + 1.f);
        float j_iou = (ij + 1.f) / (pj + gj - ij + 1.f);
        float total = ge + gj + gm + 1.f;
        float sloss = 1.f - ((ge / total) * e_iou + (gj / total) * j_iou + (gm / total) * m_iou);

        float p2g = a[12] / (a[13] + 1.f);
        float g2p = a[14] / (a[15] + 1.f);
        float med = ((p2g + g2p) * 0.5f) / 10.f;
        tri[t][0] = dice; tri[t][1] = sloss; tri[t][2] = med;
    }
    __syncthreads();
    if (t == 0) {
        float dice = 0.f, sloss = 0.f, med = 0.f;
        for (int b = 0; b < BATCH; ++b) {
            dice += tri[b][0]; sloss += tri[b][1]; med += tri[b][2];
        }
        float dice_loss  = 1.f - dice / (float)BATCH;
        float structural = sloss / (float)BATCH;
        float medial     = med / (float)BATCH;
        float avg = (dice_loss + structural + medial) / 3.f;
        float r = dice_loss  / (dice_loss  + 1.f) * avg
                + structural / (structural + 1.f) * avg
                + medial     / (medial     + 1.f) * avg;
        out[0] = r;
    }
}

extern "C" void kernel_launch(void* const* d_in, const int* in_sizes, int n_in,
                              void* d_out, int out_size, void* d_ws, size_t ws_size,
                              hipStream_t stream)
{
    const float* pred = (const float*)d_in[0];
    const float* gt   = (const float*)d_in[1];
    float* part = (float*)d_ws;
    float* out  = (float*)d_out;

    fused_kernel<<<dim3(NBLK), NT, 0, stream>>>(pred, gt, part);
    final_kernel<<<1, 512, 0, stream>>>(part, out);
}

// Round 14
// 117.654 us; speedup vs baseline: 1.0694x; 1.0694x over previous
//
#include <hip/hip_runtime.h>
#include <stdint.h>

#define BATCH 32
#define H 512
#define W 512
#define NACC 16
#define TH 32              // center rows per tile
#define HALO 9             // coverage steps a=1..9
#define RH (TH + 2*HALO)   // 50 rows incl. halo
#define NWORDS (RH*8)      // 400 mask words per image
#define NT 1024
#define NW (NT/64)         // 16 waves
#define NTILE (H/TH)       // 16
#define NBLK (NTILE*BATCH) // 512 blocks = 2/CU

// part[fid*NACC + k] per-block partials (no atomics, deterministic):
//  0: sum(p*g)  1: sum(p)  2: sum(g)
//  3: cnt_pe 4: cnt_pm 5: cnt_pj  6: cnt_ge 7: cnt_gm 8: cnt_gj
//  9: int_e 10: int_m 11: int_j
// 12: dsum_p2g 13: cnt_p2g 14: dsum_g2p 15: cnt_g2p

// LB(NT,8) forces 64-VGPR budget -> spill storm (R7/R8). LB(NT,4) is safe.
__global__ __launch_bounds__(NT, 4) void fused_kernel(
    const float* __restrict__ pred, const float* __restrict__ gt,
    float* __restrict__ part)
{
    __shared__ uint64_t MpS[NWORDS + 2];   // single-buffer + pad word each end
    __shared__ uint64_t MgS[NWORDS + 2];
    __shared__ float    EC[2][TH];         // pred colsums at cols 255|256
    __shared__ float    redf[NW][2];
    __shared__ unsigned redu[NW][5];

    uint64_t* Mp = MpS + 1;   // flat index o = row*8 + word
    uint64_t* Mg = MgS + 1;

    // fid = tile*32 + b: vertically-adjacent tiles of one image are 32 apart
    // => same XCD under mod-8 round-robin dispatch (halo rows share L2).
    int fid  = blockIdx.x;
    int b    = fid & 31;
    int tile = fid >> 5;

    const float* pimg = pred + (size_t)b * H * W;
    const float* gimg = gt   + (size_t)b * H * W;
    int y0 = tile * TH;
    int tid = threadIdx.x, lane = tid & 63, wid = tid >> 6;

    // ---- Phase 1: ballot masks + dice sums, rows y0-9..y0+40.
    // 400 word-tasks, x4 unroll: 8 global loads in flight per wave iteration.
    float v0 = 0.f, v1 = 0.f;
    for (int s0 = wid; s0 < NWORDS; s0 += 4 * NW) {
        float vp[4], vg[4];
        #pragma unroll
        for (int u = 0; u < 4; ++u) {
            int s = s0 + u * NW;
            vp[u] = 0.f; vg[u] = 0.f;
            int ry = y0 - HALO + (s >> 3);
            if (s < NWORDS && (unsigned)ry < (unsigned)H) {
                int i0 = ry * W + (s & 7) * 64 + lane;
                vp[u] = pimg[i0]; vg[u] = gimg[i0];
            }
        }
        #pragma unroll
        for (int u = 0; u < 4; ++u) {
            int s = s0 + u * NW;
            if (s < NWORDS) {                 // wave-uniform
                unsigned long long mp = __ballot(vp[u] > 0.5f);
                unsigned long long mg = __ballot(vg[u] > 0.5f);
                if (lane == 0) { Mp[s] = mp; Mg[s] = mg; }
                int r = s >> 3;
                if (r >= HALO && r < HALO + TH) {
                    v1 += vp[u];
                    v0 += (vg[u] > 0.5f) ? vp[u] : 0.f;
                }
            }
        }
    }
    if (tid == 0) { MpS[0] = 0; MpS[NWORDS + 1] = 0; MgS[0] = 0; MgS[NWORDS + 1] = 0; }

    // Stencil-wave pre-barrier prefetch (latency overlaps the barrier drain)
    bool isStencil = tid >= 512;
    int idx = tid & 511;
    int qi = idx & 127, h2 = idx >> 7;    // h2 in 0..3, 8 rows each
    int x4 = qi * 4;
    int ys = y0 + h2 * 8;
    float4 pm4 = make_float4(0, 0, 0, 0), pc4 = make_float4(0, 0, 0, 0);
    if (isStencil) {
        if (ys > 0) pm4 = *(const float4*)(pimg + (size_t)(ys - 1) * W + x4);
        pc4 = *(const float4*)(pimg + (size_t)ys * W + x4);
    }

    // pred edge colsums (cols 255,256) for the cross-wave stencil halo
    if (tid < 2 * TH) {
        int c = tid >> 5, r = tid & (TH - 1);
        int y = y0 + r, col = 255 + c;
        float sum = (y > 0     ? pimg[(size_t)(y - 1) * W + col] : 0.f)
                  +              pimg[(size_t)y * W + col]
                  + (y < H - 1 ? pimg[(size_t)(y + 1) * W + col] : 0.f);
        EC[c][r] = sum;
    }
    __syncthreads();
    // ======== NO MORE BARRIERS until the final reduce ========

    uint64_t cpack = 0ULL;      // stencil waves: 9 counters, 7-bit fields
    int dsum = 0, dcnt = 0;     // distance waves

    if (isStencil) {
        // ---- Stencil: pred via floats (rolling rows), gt via bit popcounts
        int wdx = qi >> 4;                    // gt word for this quad
        int ss = (qi & 15) * 4;               // bit offset of x4 in word
        auto win6 = [&](int rb) -> uint32_t {
            const uint64_t* row = &Mg[rb * 8];
            uint64_t bm = row[wdx];
            if (ss == 0) {
                uint64_t lo = wdx ? row[wdx - 1] : 0ULL;
                return (uint32_t)(((bm << 1) | (lo >> 63)) & 0x3FULL);
            }
            uint32_t v = (uint32_t)((bm >> (ss - 1)) & 0x3FULL);
            if (ss == 60) {
                uint64_t hi = (wdx < 7) ? row[wdx + 1] : 0ULL;
                v |= ((uint32_t)hi & 1u) << 5;
            }
            return v;
        };
        int rb0 = h2 * 8 + HALO - 1;          // bit-row of (ys-1)
        uint32_t wU = win6(rb0), wM = win6(rb0 + 1);

        for (int r = 0; r < 8; ++r) {
            int y = ys + r;
            float4 pp4 = (y < H - 1) ? *(const float4*)(pimg + (size_t)(y + 1) * W + x4)
                                     : make_float4(0, 0, 0, 0);
            uint32_t wD = win6(rb0 + 2 + r);
            int ry = h2 * 8 + r;

            float ps[6];
            ps[1] = pm4.x + pc4.x + pp4.x; ps[2] = pm4.y + pc4.y + pp4.y;
            ps[3] = pm4.z + pc4.z + pp4.z; ps[4] = pm4.w + pc4.w + pp4.w;
            float psl = __shfl_up(ps[4], 1, 64);
            float psr = __shfl_down(ps[1], 1, 64);
            if (lane == 0)  psl = (qi == 0)   ? 0.f : EC[0][ry];
            if (lane == 63) psr = (qi == 127) ? 0.f : EC[1][ry];
            ps[0] = psl; ps[5] = psr;

            float pcv[4] = {pc4.x, pc4.y, pc4.z, pc4.w};
            #pragma unroll
            for (int j = 0; j < 4; ++j) {
                float np = ps[j] + ps[j + 1] + ps[j + 2] - pcv[j];
                bool pon = pcv[j] > 0.5f;
                bool pe  = pon && (np == 1.f);
                bool pmb = pon && (np == 2.f);
                bool pjb = pon && (np > 2.f);
                uint32_t n9 = ((wU >> j) & 7u) | (((wM >> j) & 7u) << 3) | (((wD >> j) & 7u) << 6);
                uint32_t cen = (wM >> (j + 1)) & 1u;
                int ng = __popc(n9) - (int)cen;
                bool gon = cen != 0u;
                bool ge  = gon && (ng == 1);
                bool gmb = gon && (ng == 2);
                bool gjb = gon && (ng > 2);
                cpack += (uint64_t)pe
                       | ((uint64_t)pmb << 7)
                       | ((uint64_t)pjb << 14)
                       | ((uint64_t)ge  << 21)
                       | ((uint64_t)gmb << 28)
                       | ((uint64_t)gjb << 35)
                       | ((uint64_t)(pe  && ge)  << 42)
                       | ((uint64_t)(pmb && gmb) << 49)
                       | ((uint64_t)(pjb && gjb) << 56);
            }
            pm4 = pc4; pc4 = pp4; wU = wM; wM = wD;
        }
    } else {
        // ---- Distance: barrier-free register dilation (verified R10-R12).
        // C_a = S_a(V_a); incremental C_a = C_{a-1}|S_{a-1}(N_a)|shift_a(V_a)
        bool isP = tid < 256;                  // waves 0-3: p2g; 4-7: g2p
        int di = tid & 255;
        int o  = (HALO + (di >> 3)) * 8 + (di & 7);  // rc in [9,40]
        int w  = di & 7;
        bool wL = (w > 0), wR = (w < 7);
        const uint64_t* MT = isP ? Mp : Mg;
        const uint64_t* MV = isP ? Mg : Mp;

        uint64_t T = MT[o];
        dcnt = __popcll(T);
        dsum = dcnt;                           // a=0 baseline (dist >= 1)
        uint64_t VM = MV[o];
        uint64_t VL = wL ? MV[o - 1] : 0ULL;
        uint64_t VR = wR ? MV[o + 1] : 0ULL;
        uint64_t C = VM;

        #pragma unroll
        for (int a = 1; a <= 9; ++a) {
            int lo = o - 8 * a, hi = o + 8 * a;
            uint64_t NM = MV[lo] | MV[hi];
            uint64_t NL = wL ? (MV[lo - 1] | MV[hi - 1]) : 0ULL;
            uint64_t NR = wR ? (MV[lo + 1] | MV[hi + 1]) : 0ULL;
            uint64_t SL = NL, SM = NM, SR = NR;
            const int m = a - 1;
            if (m >= 1) {
                SM |= (SM << 1) | (SM >> 1) | (SL >> 63) | (SR << 63);
                SL |= SL << 1; SR |= SR >> 1;
            }
            if (m >= 2) {
                const int s = (m == 2) ? 1 : 2;
                SM |= (SM << s) | (SM >> s) | (SL >> (64 - s)) | (SR << (64 - s));
                SL |= SL << s; SR |= SR >> s;
            }
            if (m >= 4) {
                const int s = (m - 3 < 4) ? (m - 3) : 4;
                SM |= (SM << s) | (SM >> s) | (SL >> (64 - s)) | (SR << (64 - s));
                SL |= SL << s; SR |= SR >> s;
            }
            if (m >= 8) {
                const int s = m - 7;
                SM |= (SM << s) | (SM >> s) | (SL >> (64 - s)) | (SR << (64 - s));
                SL |= SL << s; SR |= SR >> s;
            }
            C |= SM;
            VL |= NL; VM |= NM; VR |= NR;
            C |= (VM << a) | (VM >> a) | (VL >> (64 - a)) | (VR << (64 - a));
            dsum += __popcll(T & ~C);
        }
    }

    // ---- Packed reductions: 2 floats + 5 u32 (16-bit fields; wave sums
    // bounded: counters <= 64*32, dsum <= 64*640 < 2^16) -> 7 butterflies.
    unsigned r0, r1, r2, r3, r4;
    if (isStencil) {
        unsigned c3  = (unsigned)( cpack        & 0x7F);
        unsigned c4  = (unsigned)((cpack >> 7 ) & 0x7F);
        unsigned c5  = (unsigned)((cpack >> 14) & 0x7F);
        unsigned c6  = (unsigned)((cpack >> 21) & 0x7F);
        unsigned c7  = (unsigned)((cpack >> 28) & 0x7F);
        unsigned c8  = (unsigned)((cpack >> 35) & 0x7F);
        unsigned c9  = (unsigned)((cpack >> 42) & 0x7F);
        unsigned c10 = (unsigned)((cpack >> 49) & 0x7F);
        unsigned c11 = (unsigned)((cpack >> 56) & 0x7F);
        r0 = c3 | (c4 << 16); r1 = c5 | (c6 << 16); r2 = c7 | (c8 << 16);
        r3 = c9 | (c10 << 16); r4 = c11;
    } else {
        r0 = (unsigned)dsum | ((unsigned)dcnt << 16);
        r1 = 0; r2 = 0; r3 = 0; r4 = 0;
    }
    #pragma unroll
    for (int off = 32; off; off >>= 1) {
        v0 += __shfl_down(v0, off, 64);
        v1 += __shfl_down(v1, off, 64);
        r0 += __shfl_down(r0, off, 64);
        r1 += __shfl_down(r1, off, 64);
        r2 += __shfl_down(r2, off, 64);
        r3 += __shfl_down(r3, off, 64);
        r4 += __shfl_down(r4, off, 64);
    }
    if (lane == 0) {
        redf[wid][0] = v0; redf[wid][1] = v1;
        redu[wid][0] = r0; redu[wid][1] = r1; redu[wid][2] = r2;
        redu[wid][3] = r3; redu[wid][4] = r4;
    }
    __syncthreads();
    if (tid < 16) {
        int k = tid;
        float s = 0.f;
        if (k < 2) {
            #pragma unroll
            for (int wv = 0; wv < NW; ++wv) s += redf[wv][k];
        } else if (k == 2) {               // sum(g) = dcnt_g (waves 4-7 high)
            unsigned u = 0;
            for (int wv = 4; wv < 8; ++wv) u += redu[wv][0] >> 16;
            s = (float)u;
        } else if (k <= 10) {              // counters from stencil waves 8-15
            int pair = (k - 3) >> 1, hi = (k - 3) & 1;
            unsigned u = 0;
            for (int wv = 8; wv < 16; ++wv) u += (redu[wv][pair] >> (hi * 16)) & 0xFFFFu;
            s = (float)u;
        } else if (k == 11) {
            unsigned u = 0;
            for (int wv = 8; wv < 16; ++wv) u += redu[wv][4];
            s = (float)u;
        } else {                           // 12..15: dsum/dcnt p (0-3) g (4-7)
            int base = (k < 14) ? 0 : 4, hi = k & 1;
            unsigned u = 0;
            for (int wv = base; wv < base + 4; ++wv)
                u += (redu[wv][0] >> (hi * 16)) & 0xFFFFu;
            s = (float)u;
        }
        part[fid * NACC + k] = s;
    }
}

// ---------------------------------------------------------------------------
// Final: reduce 512x16 partials -> 32x16 -> scalar. One block, deterministic.
// ---------------------------------------------------------------------------
__global__ __launch_bounds__(512) void final_kernel(
    const float* __restrict__ part, float* __restrict__ out)
{
    __shared__ float sacc[BATCH][NACC];
    __shared__ float tri[BATCH][3];
    int t = threadIdx.x;
    {
        int b = t >> 4, k = t & 15;
        float s = 0.f;
        #pragma unroll 4
        for (int j = 0; j < NTILE; ++j)            // fid = j*32 + b
            s += part[((j << 5) + b) * NACC + k];
        sacc[b][k] = s;
    }
    __syncthreads();
    if (t < BATCH) {
        const float* a = sacc[t];
        float inter = a[0], psum = a[1], gsum = a[2];
        float dice = (2.f * inter + 1.f) / (psum + gsum + 1.f);

        float pe = a[3], pm = a[4], pj = a[5];
        float ge = a[6], gm = a[7], gj = a[8];
        float ie = a[9], im = a[10], ij = a[11];
        float e_iou = (ie + 1.f) / (pe + ge - ie + 1.f);
        float m_iou = (im + 1.f) / (pm + gm - im + 1.f);
        float j_iou = (ij + 1.f) / (pj + gj - ij + 1.f);
        float total = ge + gj + gm + 1.f;
        float sloss = 1.f - ((ge / total) * e_iou + (gj / total) * j_iou + (gm / total) * m_iou);

        float p2g = a[12] / (a[13] + 1.f);
        float g2p = a[14] / (a[15] + 1.f);
        float med = ((p2g + g2p) * 0.5f) / 10.f;
        tri[t][0] = dice; tri[t][1] = sloss; tri[t][2] = med;
    }
    __syncthreads();
    if (t == 0) {
        float dice = 0.f, sloss = 0.f, med = 0.f;
        for (int b = 0; b < BATCH; ++b) {
            dice += tri[b][0]; sloss += tri[b][1]; med += tri[b][2];
        }
        float dice_loss  = 1.f - dice / (float)BATCH;
        float structural = sloss / (float)BATCH;
        float medial     = med / (float)BATCH;
        float avg = (dice_loss + structural + medial) / 3.f;
        float r = dice_loss  / (dice_loss  + 1.f) * avg
                + structural / (structural + 1.f) * avg
                + medial     / (medial     + 1.f) * avg;
        out[0] = r;
    }
}

extern "C" void kernel_launch(void* const* d_in, const int* in_sizes, int n_in,
                              void* d_out, int out_size, void* d_ws, size_t ws_size,
                              hipStream_t stream)
{
    const float* pred = (const float*)d_in[0];
    const float* gt   = (const float*)d_in[1];
    float* part = (float*)d_ws;
    float* out  = (float*)d_out;

    fused_kernel<<<dim3(NBLK), NT, 0, stream>>>(pred, gt, part);
    final_kernel<<<1, 512, 0, stream>>>(part, out);
}